// Round 9
// baseline (196.576 us; speedup 1.0000x reference)
//
#include <hip/hip_runtime.h>
#include <stdint.h>

#define NEG_SLOPE 0.01f
#define HPG 32        // heads per block in k4_fused == bucket size
#define TSTR 72       // padded T row stride (halfwords)
#define BSH 5         // head-bucket shift: bucket = head >> 5 (32 heads)
#define NBMX 3200     // max buckets (N=100K -> 3125)
#define K1CH 16384    // edges per binning block
#define CAP3 1024     // per-bucket staging capacity (mean 400, +31 sigma)

typedef float f32x4 __attribute__((ext_vector_type(4)));
typedef short short8 __attribute__((ext_vector_type(8)));
typedef unsigned int u32;

// DPP butterfly adds (VALU): 0xB1 quad_perm xor1, 0x4E quad_perm xor2,
// 0x141 row_half_mirror, 0x128 row_ror:8 (xor-8 within the 16-lane row).
#define DPPADD(v, ctrl) ((v) + __int_as_float(__builtin_amdgcn_update_dpp( \
        0, __float_as_int(v), (ctrl), 0xF, 0xF, true)))

__device__ inline short f2bf(float f) {
    union { float f; uint32_t u; } x; x.f = f;
    uint32_t r = x.u + 0x7FFF + ((x.u >> 16) & 1);   // RNE
    return (short)(r >> 16);
}
__device__ inline float bf2f(unsigned short u) {
    union { uint32_t u; float f; } x; x.u = ((uint32_t)u) << 16; return x.f;
}

// ---- kA: fused {bucket-major edge bin} + {ego cvt + W^T pack} --------------
// Binning blocks [0,nblk): count per 32-head bucket in LDS; ONE global
// atomicAdd per (block,bucket) reserves a range in staging[bucket][...];
// pass 2 places. rec = tail | type<<20 | (h&31)<<24.
// Blocks [nblk,...): ego fp32->bf16 + W frag pack.
__global__ void __launch_bounds__(512) kA(
        const int* __restrict__ head, const int* __restrict__ tail,
        const int* __restrict__ etype, int E, int NB, int nblk,
        u32* __restrict__ staging, int* bucket_cur,
        const float* __restrict__ ego, unsigned short* __restrict__ ego_bf,
        int NE8, const float* __restrict__ rw, short* __restrict__ wfrag) {
    int t = threadIdx.x;
    int bid = blockIdx.x;
    if (bid < nblk) {
        __shared__ int lcnt[NBMX], lbase[NBMX], lfill[NBMX];
        for (int b = t; b < NBMX; b += 512) lcnt[b] = 0;
        __syncthreads();
        long long base = (long long)bid * K1CH;
        #pragma unroll
        for (int s = 0; s < K1CH / 512; ++s) {       // pass 1: count
            long long e = base + t + s * 512;
            if (e < E) atomicAdd(&lcnt[head[e] >> BSH], 1);
        }
        __syncthreads();
        for (int b = t; b < NB; b += 512) {          // one reservation/bucket
            int c = lcnt[b];
            lbase[b] = c ? atomicAdd(&bucket_cur[b], c) : 0;
            lfill[b] = 0;
        }
        __syncthreads();
        #pragma unroll
        for (int s = 0; s < K1CH / 512; ++s) {       // pass 2: place
            long long e = base + t + s * 512;
            if (e < E) {
                int h = head[e];
                int bk = h >> BSH;
                int rk = atomicAdd(&lfill[bk], 1);
                int pos = lbase[bk] + rk;
                if (pos >= CAP3) pos = CAP3 - 1;     // defensive clamp
                staging[(size_t)bk * CAP3 + pos] =
                    (u32)tail[e] | ((u32)etype[e] << 20) | ((u32)(h & 31) << 24);
            }
        }
    } else {
        int ib = bid - nblk;
        if (ib < 16) {                               // W^T frag pack, r = ib
            int r = ib;
            int lane = t & 63;
            int c = lane & 15, q = lane >> 4;
            int pair = t >> 6;                       // 8 waves -> 8 pairs
            int t4 = pair >> 1, kh = pair & 1;
            int m = t4 * 16 + c;
            short8 f;
            for (int j = 0; j < 8; ++j) {
                int k = kh * 32 + q * 8 + j;
                f[j] = f2bf(rw[r * 4096 + k * 64 + m]);
            }
            *(short8*)(wfrag + ((size_t)((r * 4 + t4) * 2 + kh) * 64 + lane) * 8) = f;
        }
        int i = ib * 512 + t;
        if (i < NE8) {
            const float4* p = (const float4*)ego + (size_t)i * 2;
            float4 a = p[0], b = p[1];
            short8 v;
            v[0] = f2bf(a.x); v[1] = f2bf(a.y); v[2] = f2bf(a.z); v[3] = f2bf(a.w);
            v[4] = f2bf(b.x); v[5] = f2bf(b.y); v[6] = f2bf(b.z); v[7] = f2bf(b.w);
            *(short8*)(ego_bf + (size_t)i * 8) = v;
        }
    }
}

// ---- K4: phase0 LDS head-sort + phase1 transform + phase2 score/aggregate --
// Block b == bucket b (32 heads). Phase 0: read this bucket's ~400 staging
// records (coalesced), count/scan/place head-sorted into LDS lrec — replaces
// kB, recs2, head_off entirely. Phase 2 reads records via LDS broadcast.
__global__ void __launch_bounds__(512, 4) k4_fused(
        const unsigned short* __restrict__ ego_bf,
        const short* __restrict__ wfrag,
        const u32* __restrict__ staging,
        const int* __restrict__ bucket_cur,
        float* __restrict__ out, int N) {
    __shared__ unsigned short T[16 * HPG * TSTR];   // 73,728 B
    __shared__ u32 lrec[CAP3];                      // 4 KB
    __shared__ int lhc[HPG], lofs[HPG], lcn[HPG];
    int tid = threadIdx.x;
    int wave = tid >> 6;
    int lane = tid & 63;
    int c = lane & 15, q = lane >> 4;
    int b = blockIdx.x;
    int hb = b * HPG;

    // ---------------- phase 0: bucket sort into LDS -----------------------
    if (tid < HPG) lhc[tid] = 0;
    __syncthreads();
    int cnt_raw = bucket_cur[b];
    int cntb = cnt_raw > CAP3 ? CAP3 : cnt_raw;
    const u32* sb = staging + (size_t)b * CAP3;
    u32 r0 = 0, r1 = 0; int rk0 = -1, rk1 = -1;
    if (tid < cntb)       { r0 = sb[tid];       rk0 = atomicAdd(&lhc[r0 >> 24], 1); }
    if (tid + 512 < cntb) { r1 = sb[tid + 512]; rk1 = atomicAdd(&lhc[r1 >> 24], 1); }
    __syncthreads();
    if (tid < 64) {                                  // scan 32 counters, 1 wave
        int v = (lane < HPG) ? lhc[lane] : 0;
        int inc = v;
        for (int off = 1; off < HPG; off <<= 1) {
            int u = __shfl_up(inc, off);
            if (lane >= off) inc += u;
        }
        if (lane < HPG) { lofs[lane] = inc - v; lcn[lane] = v; }
    }
    __syncthreads();
    if (rk0 >= 0) lrec[lofs[r0 >> 24] + rk0] = r0;
    if (rk1 >= 0) lrec[lofs[r1 >> 24] + rk1] = r1;

    // ---------------- phase 1: per-wave 2 types x 32 heads ----------------
    for (int t = 0; t < 2; ++t) {
        int r = wave * 2 + t;
        const short* wp = wfrag + (size_t)r * 4096;
        short8 wf[4][2];
        #pragma unroll
        for (int t4 = 0; t4 < 4; ++t4)
            #pragma unroll
            for (int kh = 0; kh < 2; ++kh)
                wf[t4][kh] = *(const short8*)(wp + ((size_t)((t4 * 2 + kh) * 64 + lane)) * 8);
        #pragma unroll
        for (int hf = 0; hf < 2; ++hf) {
            int hrow = hb + hf * 16 + c;
            if (hrow >= N) hrow = N - 1;           // clamp; garbage T never read
            const unsigned short* hr = ego_bf + (size_t)hrow * 64;
            short8 b0 = *(const short8*)(hr + q * 8);
            short8 b1 = *(const short8*)(hr + 32 + q * 8);
            #pragma unroll
            for (int t4 = 0; t4 < 4; ++t4) {
                f32x4 a = {0.f, 0.f, 0.f, 0.f};
                a = __builtin_amdgcn_mfma_f32_16x16x32_bf16(wf[t4][0], b0, a, 0, 0, 0);
                a = __builtin_amdgcn_mfma_f32_16x16x32_bf16(wf[t4][1], b1, a, 0, 0, 0);
                ushort4 us;
                us.x = (unsigned short)f2bf(a[0]);
                us.y = (unsigned short)f2bf(a[1]);
                us.z = (unsigned short)f2bf(a[2]);
                us.w = (unsigned short)f2bf(a[3]);
                *(ushort4*)&T[(size_t)(r * HPG + hf * 16 + c) * TSTR + t4 * 16 + q * 4] = us;
            }
        }
    }
    __syncthreads();                               // covers T and lrec writes

    // ---------------- phase 2: quarter (wave,q) owns head hb + wave*4 + q --
    int hql = wave * 4 + q;
    int h = hb + hql;
    if (h >= N) return;
    int lq = c;                   // lane within quarter
    int g2 = lq >> 3, c8 = lq & 7;
    int s0 = lofs[hql];
    int cnt = lcn[hql];
    int nbt = (cnt + 15) >> 4;
    float acc[8] = {0.f, 0.f, 0.f, 0.f, 0.f, 0.f, 0.f, 0.f};
    float den = 0.f;

    auto recAt = [&](int b2, int j) -> u32 {       // LDS broadcast per 8-group
        int idx = b2 * 16 + j * 2 + g2;
        return (idx < cnt) ? lrec[s0 + idx] : 0;
    };

    u32 rjA[8]; short8 rowsA[8];
    #pragma unroll
    for (int j = 0; j < 8; ++j) rjA[j] = recAt(0, j);
    #pragma unroll
    for (int j = 0; j < 8; ++j)
        rowsA[j] = *(const short8*)(ego_bf + (size_t)(rjA[j] & 0xFFFFF) * 64 + c8 * 8);
    for (int b2 = 0; b2 < nbt; ++b2) {
        u32 rjB[8]; short8 rowsB[8];
        bool more = (b2 + 1 < nbt);
        if (more) {
            #pragma unroll
            for (int j = 0; j < 8; ++j) rjB[j] = recAt(b2 + 1, j);
            #pragma unroll
            for (int j = 0; j < 8; ++j)            // G(b2+1) in flight over C(b2)
                rowsB[j] = *(const short8*)(ego_bf + (size_t)(rjB[j] & 0xFFFFF) * 64 + c8 * 8);
        }
        int ng = cnt - b2 * 16; if (ng > 16) ng = 16;
        #pragma unroll
        for (int sIt = 0; sIt < 8; ++sIt) {        // C(b2)
            if (sIt * 2 < ng) {
                int ty = (rjA[sIt] >> 20) & 15;
                short8 trw = *(const short8*)&T[(size_t)(ty * HPG + hql) * TSTR + c8 * 8];
                float rf[8];
                float sa = 0.f, sb2 = 0.f;
                #pragma unroll
                for (int k = 0; k < 4; ++k) {
                    rf[k] = bf2f((unsigned short)rowsA[sIt][k]);
                    sa += rf[k] * bf2f((unsigned short)trw[k]);
                }
                #pragma unroll
                for (int k = 4; k < 8; ++k) {
                    rf[k] = bf2f((unsigned short)rowsA[sIt][k]);
                    sb2 += rf[k] * bf2f((unsigned short)trw[k]);
                }
                float s = sa + sb2;
                s = DPPADD(s, 0xB1);               // xor1
                s = DPPADD(s, 0x4E);               // xor2
                s = DPPADD(s, 0x141);              // other quad
                float lr = s > 0.f ? s : NEG_SLOPE * s;
                float w = (sIt * 2 + g2 < ng) ? __expf(lr) : 0.f;
                den += w;
                #pragma unroll
                for (int k = 0; k < 8; ++k) acc[k] += w * rf[k];
            }
        }
        if (more) {
            #pragma unroll
            for (int j = 0; j < 8; ++j) { rjA[j] = rjB[j]; rowsA[j] = rowsB[j]; }
        }
    }
    den = DPPADD(den, 0x128);                      // combine 2 edge slots
    #pragma unroll
    for (int k = 0; k < 8; ++k) acc[k] = DPPADD(acc[k], 0x128);
    if (g2 == 0) {
        float sc = (cnt > 0) ? 1.f / (den * (float)cnt) : 0.f;
        float4 v0 = {acc[0] * sc, acc[1] * sc, acc[2] * sc, acc[3] * sc};
        float4 v1 = {acc[4] * sc, acc[5] * sc, acc[6] * sc, acc[7] * sc};
        float* op = out + (size_t)h * 64 + c8 * 8;
        *(float4*)op = v0;
        *(float4*)(op + 4) = v1;
    }
}

extern "C" void kernel_launch(void* const* d_in, const int* in_sizes, int n_in,
                              void* d_out, int out_size, void* d_ws, size_t ws_size,
                              hipStream_t stream) {
    const float* ego = (const float*)d_in[0];
    const float* rw  = (const float*)d_in[1];
    const int* eidx  = (const int*)d_in[2];
    const int* etyp  = (const int*)d_in[3];
    int N = in_sizes[0] / 64;
    int E = in_sizes[3];
    const int* head = eidx;
    const int* tail = eidx + E;
    float* out = (float*)d_out;

    char* ws = (char*)d_ws;
    size_t o = 0;
    auto take = [&](size_t bytes) -> char* {
        char* p = ws + o;
        o = (o + bytes + 255) & ~(size_t)255;
        return p;
    };
    int NB = (N + HPG - 1) >> BSH;
    if (NB > NBMX) NB = NBMX;              // defensive; N=100K -> 3125
    int nblk = (E + K1CH - 1) / K1CH;      // 1.25M -> 77
    int NE8 = N * 8;
    int nbI = (NE8 + 511) / 512;           // init blocks (>= 16 for W pack)
    if (nbI < 16) nbI = 16;
    unsigned short* ego_bf = (unsigned short*)take((size_t)N * 64 * 2);
    short* wfrag    = (short*)take(16 * 4096 * 2);
    u32* staging    = (u32*)take((size_t)NB * CAP3 * 4);
    int* bucket_cur = (int*)take((size_t)NBMX * 4);
    (void)ws_size; (void)n_in; (void)out_size;

    hipMemsetAsync(bucket_cur, 0, (size_t)NBMX * 4, stream);
    kA<<<nblk + nbI, 512, 0, stream>>>(head, tail, etyp, E, NB, nblk,
                                       staging, bucket_cur,
                                       ego, ego_bf, NE8, rw, wfrag);
    k4_fused<<<NB, 512, 0, stream>>>(ego_bf, wfrag, staging, bucket_cur,
                                     out, N);
}